// Round 9
// baseline (68.326 us; speedup 1.0000x reference)
//
#include <hip/hip_runtime.h>
#include <math.h>

#define GG 2000   // num_graphs (reference constant)

typedef short bf16x8 __attribute__((ext_vector_type(8)));
typedef float f32x4  __attribute__((ext_vector_type(4)));

__device__ __forceinline__ unsigned int cvtpk(float lo, float hi) {
    unsigned int r;
    asm volatile("v_cvt_pk_bf16_f32 %0, %1, %2" : "=v"(r) : "v"(lo), "v"(hi));
    return r;   // bits[15:0]=bf16(lo), [31:16]=bf16(hi)
}
__device__ __forceinline__ unsigned short f2b_up(float f) {   // round-half-up, 2 instr
    return (unsigned short)((__float_as_uint(f) + 0x8000u) >> 16);
}

// seg[g] = first node index with batch[node] >= g. Boundary scatter over sorted batch.
__global__ void seg_kernel(const int* __restrict__ batch, int* __restrict__ seg, int n) {
    int i = blockIdx.x * blockDim.x + threadIdx.x;
    if (i >= n) return;
    int b1 = batch[i];
    int b0 = (i == 0) ? -1 : batch[i - 1];
    for (int g = b0 + 1; g <= b1; ++g) seg[g] = i;
    if (i == n - 1) { for (int g = b1 + 1; g <= GG; ++g) seg[g] = n; }
}

// ---------------- Phase A: scores = tanh(x@w1^T)@w2^T, flat 64-node tiles ----------------
__global__ __launch_bounds__(256, 3) void score_kernel(
    const float* __restrict__ x, const float* __restrict__ w1,
    const float* __restrict__ w2, float* __restrict__ scores,
    int n_nodes, int ntile)
{
    __shared__ __align__(16) unsigned short w1b[16384];  // [128 hid][128 k] bf16, slot^=(row&7)
    __shared__ __align__(16) unsigned short xb[8192];    // [64 n][128 k] bf16; h aliases per-wave rows

    const int t = threadIdx.x;
    const int lane = t & 63;
    const int w = t >> 6;
    const int l15 = lane & 15;
    const int lg = lane >> 4;
    const int srow = t >> 5;      // staging row within octet
    const int sq = t & 31;        // staging float4 column

    // ---- stage w1 -> bf16 LDS once per block (cvt_pk) ----
#pragma unroll
    for (int i = 0; i < 16; ++i) {
        int f4 = i * 256 + t;                  // 4096 float4
        int row = f4 >> 5, q = f4 & 31;
        float4 v = ((const float4*)w1)[f4];
        uint2 p;
        p.x = cvtpk(v.x, v.y); p.y = cvtpk(v.z, v.w);
        int slot = (q >> 1) ^ (row & 7);
        *(uint2*)((char*)w1b + row * 256 + slot * 16 + (q & 1) * 8) = p;
    }
    // ---- w2 b-frags in regs: lane -> col o=l15 (rows 8..15 zero) ----
    bf16x8 w2f[4];
    {
        const int o = l15;
#pragma unroll
        for (int ks = 0; ks < 4; ++ks) {
            float tmp[8];
            if (o < 8) {
                float4 u0 = ((const float4*)w2)[o * 32 + ks * 8 + lg * 2];
                float4 u1 = ((const float4*)w2)[o * 32 + ks * 8 + lg * 2 + 1];
                tmp[0]=u0.x; tmp[1]=u0.y; tmp[2]=u0.z; tmp[3]=u0.w;
                tmp[4]=u1.x; tmp[5]=u1.y; tmp[6]=u1.z; tmp[7]=u1.w;
            } else {
#pragma unroll
                for (int i = 0; i < 8; ++i) tmp[i] = 0.f;
            }
            bf16x8 r;
#pragma unroll
            for (int i = 0; i < 8; ++i) {
                unsigned int u = cvtpk(tmp[i], tmp[i]);
                r[i] = (short)(u & 0xFFFF);
            }
            w2f[ks] = r;
        }
    }
    __syncthreads();   // w1b staged
    // ---- hoist w1 B-frags nt=0,1 into registers (32 VGPR) ----
    bf16x8 bfreg[4][2];
#pragma unroll
    for (int ks = 0; ks < 4; ++ks)
#pragma unroll
        for (int nt = 0; nt < 2; ++nt) {
            int brow = nt * 16 + l15;
            int slot = (ks * 4 + lg) ^ (brow & 7);
            bfreg[ks][nt] = *(bf16x8*)((char*)w1b + brow * 256 + slot * 16);
        }

    char* myhb = (char*)xb + w * 4096;   // wave-private 16 rows (x then h)

    // ---- preload tile 0 ----
    int tile = blockIdx.x;
    float4 pre[8];
    if (tile < ntile) {
#pragma unroll
        for (int i = 0; i < 8; ++i) {
            int node = tile * 64 + i * 8 + srow;
            if (node >= n_nodes) node = n_nodes - 1;
            pre[i] = ((const float4*)x)[(size_t)node * 32 + sq];
        }
    }

    for (; tile < ntile; tile += gridDim.x) {
        const int base = tile * 64;
        __syncthreads();                 // prev tile fully consumed (and bfreg reads on iter 0)
        // ---- write staged regs -> xb (cvt_pk) ----
#pragma unroll
        for (int i = 0; i < 8; ++i) {
            int row = i * 8 + srow;
            uint2 p;
            p.x = cvtpk(pre[i].x, pre[i].y); p.y = cvtpk(pre[i].z, pre[i].w);
            int slot = (sq >> 1) ^ (row & 7);
            *(uint2*)((char*)xb + row * 256 + slot * 16 + (sq & 1) * 8) = p;
        }
        __syncthreads();                 // xb ready
        // ---- T14: issue next tile's loads now; they complete under compute ----
        {
            int ntile2 = tile + gridDim.x;
            if (ntile2 < ntile) {
#pragma unroll
                for (int i = 0; i < 8; ++i) {
                    int node = ntile2 * 64 + i * 8 + srow;
                    if (node >= n_nodes) node = n_nodes - 1;
                    pre[i] = ((const float4*)x)[(size_t)node * 32 + sq];
                }
            }
        }
        // ---- GEMM1: wave rows w*16..+15 x 128 hidden ----
        f32x4 acc1[8];
#pragma unroll
        for (int nt = 0; nt < 8; ++nt)
#pragma unroll
            for (int r = 0; r < 4; ++r) acc1[nt][r] = 0.f;
#pragma unroll
        for (int ks = 0; ks < 4; ++ks) {
            int arow = w * 16 + l15;
            int aslot = (ks * 4 + lg) ^ (arow & 7);
            bf16x8 af = *(const bf16x8*)((char*)xb + arow * 256 + aslot * 16);
#pragma unroll
            for (int nt = 0; nt < 2; ++nt)
                acc1[nt] = __builtin_amdgcn_mfma_f32_16x16x32_bf16(af, bfreg[ks][nt], acc1[nt], 0, 0, 0);
#pragma unroll
            for (int nt = 2; nt < 8; ++nt) {
                int brow = nt * 16 + l15;
                int bslot = (ks * 4 + lg) ^ (brow & 7);
                bf16x8 bfr = *(bf16x8*)((char*)w1b + brow * 256 + bslot * 16);
                acc1[nt] = __builtin_amdgcn_mfma_f32_16x16x32_bf16(af, bfr, acc1[nt], 0, 0, 0);
            }
        }
        // ---- tanh -> own rows (aliases xb; wave-private, in-wave LDS order) ----
#pragma unroll
        for (int nt = 0; nt < 8; ++nt)
#pragma unroll
            for (int r = 0; r < 4; ++r) {
                float aa = acc1[nt][r];
                float eo = __expf(-2.f * fabsf(aa));
                float th = copysignf((1.f - eo) * __builtin_amdgcn_rcpf(1.f + eo), aa);
                int m = lg * 4 + r;
                int n = nt * 16 + l15;
                int slot = (n >> 3) ^ (m & 7);
                *(unsigned short*)(myhb + m * 256 + slot * 16 + (n & 7) * 2) = f2b_up(th);
            }
        // ---- GEMM2: scores for the wave's 16 rows x 8 heads (cols 8..15 pad) ----
        f32x4 acc2;
#pragma unroll
        for (int r = 0; r < 4; ++r) acc2[r] = 0.f;
#pragma unroll
        for (int ks = 0; ks < 4; ++ks) {
            int slot = (ks * 4 + lg) ^ (l15 & 7);
            bf16x8 hf = *(bf16x8*)(myhb + l15 * 256 + slot * 16);
            acc2 = __builtin_amdgcn_mfma_f32_16x16x32_bf16(hf, w2f[ks], acc2, 0, 0, 0);
        }
        if (l15 < 8) {
#pragma unroll
            for (int r = 0; r < 4; ++r) {
                int node = base + w * 16 + lg * 4 + r;
                if (node < n_nodes) scores[node * 8 + l15] = acc2[r];
            }
        }
    }
}

// ---------------- Phase B: per-graph max and 1/sum(exp), shfl-reduced ----------------
__global__ __launch_bounds__(256) void segstat_kernel(
    const float* __restrict__ scores, const int* __restrict__ seg,
    float* __restrict__ gmax, float* __restrict__ ginv)
{
    __shared__ float redm[256], redl[256];
    const int g = blockIdx.x, t = threadIdx.x;
    const int lane = t & 63;
    const int s = seg[g];
    const int e = seg[g + 1];
    const int o = t & 7, j = t >> 3;

    float m = -INFINITY;
    for (int n = s + j; n < e; n += 32) m = fmaxf(m, scores[n * 8 + o]);
    redm[t] = m;
    __syncthreads();
    // all threads: reduce over same o (t mod 8 preserved by the strides below)
    float M = fmaxf(fmaxf(redm[lane], redm[lane + 64]), fmaxf(redm[lane + 128], redm[lane + 192]));
    M = fmaxf(M, __shfl_xor(M, 8));
    M = fmaxf(M, __shfl_xor(M, 16));
    M = fmaxf(M, __shfl_xor(M, 32));     // M = graph max for head o (= lane&7 = t&7)
    float l = 0.f;
    for (int n = s + j; n < e; n += 32) l += __expf(scores[n * 8 + o] - M);
    redl[t] = l;
    __syncthreads();
    float L = (redl[lane] + redl[lane + 64]) + (redl[lane + 128] + redl[lane + 192]);
    L += __shfl_xor(L, 8);
    L += __shfl_xor(L, 16);
    L += __shfl_xor(L, 32);
    if (t < 8) {
        gmax[g * 8 + t] = M;
        ginv[g * 8 + t] = 1.f / L;   // inf/nan for empty graph: never consumed
    }
}

// ---------------- Phase C: out[g][o][f] = sum_n attn[n][o] * x[n][f] ----------------
__global__ __launch_bounds__(256) void out_kernel(
    const float* __restrict__ x, const float* __restrict__ scores,
    const int* __restrict__ seg, const float* __restrict__ gmax,
    const float* __restrict__ ginv, float* __restrict__ out)
{
    __shared__ __align__(16) float xsl[16 * 128];
    __shared__ __align__(16) float atl[16 * 8];
    const int g = blockIdx.x, t = threadIdx.x;
    const int s = seg[g];
    const int e = seg[g + 1];
    const int f = t & 127, ob = t >> 7;    // thread covers o in {4*ob..4*ob+3} at feature f
    const float gm = gmax[g * 8 + (t & 7)];   // for staging threads (t<128); harmless otherwise
    const float gi = ginv[g * 8 + (t & 7)];
    float a0 = 0.f, a1 = 0.f, a2 = 0.f, a3 = 0.f;

    for (int c = s; c < e; c += 16) {
        const int cnt = min(16, e - c);
        __syncthreads();   // protects prev-iter reads
#pragma unroll
        for (int i = 0; i < 2; ++i) {
            int f4 = i * 256 + t;
            int row = f4 >> 5, col4 = f4 & 31;
            if (row < cnt)
                ((float4*)xsl)[row * 32 + col4] = ((const float4*)x)[(size_t)(c + row) * 32 + col4];
        }
        if (t < 128) {
            int j = t >> 3;
            if (j < cnt)
                atl[j * 8 + (t & 7)] = __expf(scores[(c + j) * 8 + (t & 7)] - gm) * gi;
        }
        __syncthreads();
        for (int j = 0; j < cnt; ++j) {
            float xv = xsl[j * 128 + f];
            float4 a4 = ((const float4*)atl)[j * 2 + ob];
            a0 += a4.x * xv; a1 += a4.y * xv; a2 += a4.z * xv; a3 += a4.w * xv;
        }
    }
    const int gb = g * 1024 + ob * 512 + f;
    out[gb]       = a0;     // empty graph: accs are 0 = segment_sum identity
    out[gb + 128] = a1;
    out[gb + 256] = a2;
    out[gb + 384] = a3;
}

extern "C" void kernel_launch(void* const* d_in, const int* in_sizes, int n_in,
                              void* d_out, int out_size, void* d_ws, size_t ws_size,
                              hipStream_t stream)
{
    const float* x     = (const float*)d_in[0];
    const int*   batch = (const int*)d_in[1];
    const float* w1    = (const float*)d_in[2];
    const float* w2    = (const float*)d_in[3];
    const int n_nodes  = in_sizes[1];
    float* out = (float*)d_out;

    float* scores = (float*)d_ws;                          // n*8 floats
    float* gmax   = scores + (size_t)n_nodes * 8;          // GG*8
    float* ginv   = gmax + (size_t)GG * 8;                 // GG*8
    int*   seg    = (int*)(ginv + (size_t)GG * 8);         // GG+1 ints

    const int ntile = (n_nodes + 63) / 64;
    hipLaunchKernelGGL(seg_kernel,     dim3((n_nodes + 255) / 256), dim3(256), 0, stream, batch, seg, n_nodes);
    hipLaunchKernelGGL(score_kernel,   dim3(768), dim3(256), 0, stream, x, w1, w2, scores, n_nodes, ntile);
    hipLaunchKernelGGL(segstat_kernel, dim3(GG),  dim3(256), 0, stream, scores, seg, gmax, ginv);
    hipLaunchKernelGGL(out_kernel,     dim3(GG),  dim3(256), 0, stream, x, scores, seg, gmax, ginv, out);
}

// Round 10
// 60.033 us; speedup vs baseline: 1.1381x; 1.1381x over previous
//
#include <hip/hip_runtime.h>
#include <math.h>

#define GG 2000   // num_graphs (reference constant)

typedef short bf16x8 __attribute__((ext_vector_type(8)));
typedef float f32x4  __attribute__((ext_vector_type(4)));

__device__ __forceinline__ unsigned short f2b(float f) {
    unsigned int u = __float_as_uint(f);
    u += 0x7FFFu + ((u >> 16) & 1u);          // round-to-nearest-even
    return (unsigned short)(u >> 16);
}
__device__ __forceinline__ unsigned short f2b_up(float f) {   // round-half-up, 2 instr
    return (unsigned short)((__float_as_uint(f) + 0x8000u) >> 16);
}

// seg[g] = first node index with batch[node] >= g. Boundary scatter over sorted batch.
__global__ void seg_kernel(const int* __restrict__ batch, int* __restrict__ seg, int n) {
    int i = blockIdx.x * blockDim.x + threadIdx.x;
    if (i >= n) return;
    int b1 = batch[i];
    int b0 = (i == 0) ? -1 : batch[i - 1];
    for (int g = b0 + 1; g <= b1; ++g) seg[g] = i;
    if (i == n - 1) { for (int g = b1 + 1; g <= GG; ++g) seg[g] = n; }
}

// ---------------- Phase A: scores = tanh(x@w1^T)@w2^T ----------------
// 512-thr blocks (8 waves), 64-node tiles. Wave pair (grp, half): rows grp*16..+15;
// half 0 -> hidden cols 0..63 (nt 0..3), half 1 -> 64..127. Each wave: GEMM1 (16 MFMA,
// 16 B-reads), tanh (16 vals) -> wave-private h (aliases xb), GEMM2 k-half (2 MFMA),
// cross-half f32x4 partial via LDS. 3 barriers/tile, 24 waves/CU.
__global__ __launch_bounds__(512, 6) void score_kernel(
    const float* __restrict__ x, const float* __restrict__ w1,
    const float* __restrict__ w2, float* __restrict__ scores,
    int n_nodes, int ntile)
{
    __shared__ __align__(16) unsigned short w1b[16384];  // [128 hid][128 k] bf16, slot^=(row&7)
    __shared__ __align__(16) unsigned short xb[8192];    // [64 n][128 k] bf16; per-wave h aliases (2KB/wave)
    __shared__ __align__(16) f32x4 pb[4][64];            // GEMM2 partials from half=1 waves

    const int t = threadIdx.x;      // 0..511
    const int lane = t & 63;
    const int w = t >> 6;           // 0..7
    const int l15 = lane & 15;
    const int lg  = lane >> 4;
    const int grp  = w & 3;         // row group
    const int half = w >> 2;        // hidden half

    // ---- stage w1 -> bf16 LDS (8 f4/thread) ----
#pragma unroll
    for (int i = 0; i < 8; ++i) {
        int f4 = i * 512 + t;                  // 4096 float4
        int row = f4 >> 5, q = f4 & 31;
        float4 v = ((const float4*)w1)[f4];
        ushort4 p;
        p.x = f2b(v.x); p.y = f2b(v.y); p.z = f2b(v.z); p.w = f2b(v.w);
        int slot = (q >> 1) ^ (row & 7);
        *(ushort4*)((char*)w1b + row * 256 + slot * 16 + (q & 1) * 8) = p;
    }
    // ---- w2 b-frags for this wave's 2 local ks (col o = l15; rows 8..15 zero) ----
    bf16x8 w2f[2];
#pragma unroll
    for (int kk = 0; kk < 2; ++kk) {
        int ks = half * 2 + kk;
        float tmp[8];
        if (l15 < 8) {
            float4 u0 = ((const float4*)w2)[l15 * 32 + ks * 8 + lg * 2];
            float4 u1 = ((const float4*)w2)[l15 * 32 + ks * 8 + lg * 2 + 1];
            tmp[0]=u0.x; tmp[1]=u0.y; tmp[2]=u0.z; tmp[3]=u0.w;
            tmp[4]=u1.x; tmp[5]=u1.y; tmp[6]=u1.z; tmp[7]=u1.w;
        } else {
#pragma unroll
            for (int i = 0; i < 8; ++i) tmp[i] = 0.f;
        }
        bf16x8 r;
#pragma unroll
        for (int i = 0; i < 8; ++i) r[i] = (short)f2b(tmp[i]);
        w2f[kk] = r;
    }
    // ---- stage first x tile (4 f4/thread) ----
    int tile = blockIdx.x;
    if (tile < ntile) {
#pragma unroll
        for (int i = 0; i < 4; ++i) {
            int f4 = i * 512 + t;              // 2048 float4
            int row = f4 >> 5, q = f4 & 31;
            int node = tile * 64 + row; if (node >= n_nodes) node = n_nodes - 1;
            float4 v = ((const float4*)x)[(size_t)node * 32 + q];
            ushort4 p;
            p.x = f2b(v.x); p.y = f2b(v.y); p.z = f2b(v.z); p.w = f2b(v.w);
            int slot = (q >> 1) ^ (row & 7);
            *(ushort4*)((char*)xb + row * 256 + slot * 16 + (q & 1) * 8) = p;
        }
    }
    __syncthreads();   // w1b + first xb ready

    char* myhb = (char*)xb + w * 2048;   // wave-private h: [16 m][64 n'] bf16, 128B rows

    for (; tile < ntile; tile += gridDim.x) {
        const int base = tile * 64;
        // ---- GEMM1: rows grp*16..+15, global nt = half*4 + ntl ----
        f32x4 acc1[4];
#pragma unroll
        for (int ntl = 0; ntl < 4; ++ntl)
#pragma unroll
            for (int r = 0; r < 4; ++r) acc1[ntl][r] = 0.f;
#pragma unroll
        for (int ks = 0; ks < 4; ++ks) {
            int arow = grp * 16 + l15;
            int aslot = (ks * 4 + lg) ^ (arow & 7);
            bf16x8 af = *(const bf16x8*)((char*)xb + arow * 256 + aslot * 16);
#pragma unroll
            for (int ntl = 0; ntl < 4; ++ntl) {
                int brow = (half * 4 + ntl) * 16 + l15;
                int bslot = (ks * 4 + lg) ^ (brow & 7);
                bf16x8 bfr = *(bf16x8*)((char*)w1b + brow * 256 + bslot * 16);
                acc1[ntl] = __builtin_amdgcn_mfma_f32_16x16x32_bf16(af, bfr, acc1[ntl], 0, 0, 0);
            }
        }
        __syncthreads();   // all xb A-reads done before h overwrites xb
        // ---- tanh -> myhb: value (m = lg*4+r, n' = ntl*16+l15), slot = ((n'>>3)+m)&7 ----
#pragma unroll
        for (int ntl = 0; ntl < 4; ++ntl)
#pragma unroll
            for (int r = 0; r < 4; ++r) {
                float aa = acc1[ntl][r];
                float eo = __expf(-2.f * fabsf(aa));
                float th = copysignf((1.f - eo) * __builtin_amdgcn_rcpf(1.f + eo), aa);
                int m = lg * 4 + r;
                int np = ntl * 16 + l15;
                int slot = ((np >> 3) + m) & 7;
                *(unsigned short*)(myhb + m * 128 + slot * 16 + (np & 7) * 2) = f2b_up(th);
            }
        // ---- GEMM2 (own k-half): A row m = l15, k-slot = kk*4+lg ----
        f32x4 acc2;
#pragma unroll
        for (int r = 0; r < 4; ++r) acc2[r] = 0.f;
#pragma unroll
        for (int kk = 0; kk < 2; ++kk) {
            int slot = ((kk * 4 + lg) + l15) & 7;
            bf16x8 hf = *(bf16x8*)(myhb + l15 * 128 + slot * 16);
            acc2 = __builtin_amdgcn_mfma_f32_16x16x32_bf16(hf, w2f[kk], acc2, 0, 0, 0);
        }
        if (half) pb[grp][lane] = acc2;
        __syncthreads();   // partials visible; all h reads done
        if (!half) {
            f32x4 po = pb[grp][lane];
#pragma unroll
            for (int r = 0; r < 4; ++r) acc2[r] += po[r];
            if (l15 < 8) {
#pragma unroll
                for (int r = 0; r < 4; ++r) {
                    int node = base + grp * 16 + lg * 4 + r;
                    if (node < n_nodes) scores[node * 8 + l15] = acc2[r];
                }
            }
        }
        // ---- stage next tile (overwrites xb/h: safe after the barrier above) ----
        {
            int nxt = tile + gridDim.x;
            if (nxt < ntile) {
#pragma unroll
                for (int i = 0; i < 4; ++i) {
                    int f4 = i * 512 + t;
                    int row = f4 >> 5, q = f4 & 31;
                    int node = nxt * 64 + row; if (node >= n_nodes) node = n_nodes - 1;
                    float4 v = ((const float4*)x)[(size_t)node * 32 + q];
                    ushort4 p;
                    p.x = f2b(v.x); p.y = f2b(v.y); p.z = f2b(v.z); p.w = f2b(v.w);
                    int slot = (q >> 1) ^ (row & 7);
                    *(ushort4*)((char*)xb + row * 256 + slot * 16 + (q & 1) * 8) = p;
                }
            }
        }
        __syncthreads();   // next xb ready
    }
}

// ---------------- Phase B: per-graph max and 1/sum(exp), shfl-reduced ----------------
__global__ __launch_bounds__(256) void segstat_kernel(
    const float* __restrict__ scores, const int* __restrict__ seg,
    float* __restrict__ gmax, float* __restrict__ ginv)
{
    __shared__ float redm[256], redl[256];
    const int g = blockIdx.x, t = threadIdx.x;
    const int lane = t & 63;
    const int s = seg[g];
    const int e = seg[g + 1];
    const int o = t & 7, j = t >> 3;

    float m = -INFINITY;
    for (int n = s + j; n < e; n += 32) m = fmaxf(m, scores[n * 8 + o]);
    redm[t] = m;
    __syncthreads();
    float M = fmaxf(fmaxf(redm[lane], redm[lane + 64]), fmaxf(redm[lane + 128], redm[lane + 192]));
    M = fmaxf(M, __shfl_xor(M, 8));
    M = fmaxf(M, __shfl_xor(M, 16));
    M = fmaxf(M, __shfl_xor(M, 32));     // graph max for head o (= lane&7 = t&7)
    float l = 0.f;
    for (int n = s + j; n < e; n += 32) l += __expf(scores[n * 8 + o] - M);
    redl[t] = l;
    __syncthreads();
    float L = (redl[lane] + redl[lane + 64]) + (redl[lane + 128] + redl[lane + 192]);
    L += __shfl_xor(L, 8);
    L += __shfl_xor(L, 16);
    L += __shfl_xor(L, 32);
    if (t < 8) {
        gmax[g * 8 + t] = M;
        ginv[g * 8 + t] = 1.f / L;   // inf/nan for empty graph: never consumed
    }
}

// ---------------- Phase C: out[g][o][f] = sum_n attn[n][o] * x[n][f] ----------------
__global__ __launch_bounds__(256) void out_kernel(
    const float* __restrict__ x, const float* __restrict__ scores,
    const int* __restrict__ seg, const float* __restrict__ gmax,
    const float* __restrict__ ginv, float* __restrict__ out)
{
    __shared__ __align__(16) float xsl[16 * 128];
    __shared__ __align__(16) float atl[16 * 8];
    const int g = blockIdx.x, t = threadIdx.x;
    const int s = seg[g];
    const int e = seg[g + 1];
    const int f = t & 127, ob = t >> 7;
    const float gm = gmax[g * 8 + (t & 7)];
    const float gi = ginv[g * 8 + (t & 7)];
    float a0 = 0.f, a1 = 0.f, a2 = 0.f, a3 = 0.f;

    for (int c = s; c < e; c += 16) {
        const int cnt = min(16, e - c);
        __syncthreads();
#pragma unroll
        for (int i = 0; i < 2; ++i) {
            int f4 = i * 256 + t;
            int row = f4 >> 5, col4 = f4 & 31;
            if (row < cnt)
                ((float4*)xsl)[row * 32 + col4] = ((const float4*)x)[(size_t)(c + row) * 32 + col4];
        }
        if (t < 128) {
            int j = t >> 3;
            if (j < cnt)
                atl[j * 8 + (t & 7)] = __expf(scores[(c + j) * 8 + (t & 7)] - gm) * gi;
        }
        __syncthreads();
        for (int j = 0; j < cnt; ++j) {
            float xv = xsl[j * 128 + f];
            float4 a4 = ((const float4*)atl)[j * 2 + ob];
            a0 += a4.x * xv; a1 += a4.y * xv; a2 += a4.z * xv; a3 += a4.w * xv;
        }
    }
    const int gb = g * 1024 + ob * 512 + f;
    out[gb]       = a0;     // empty graph: accs are 0 = segment_sum identity
    out[gb + 128] = a1;
    out[gb + 256] = a2;
    out[gb + 384] = a3;
}

extern "C" void kernel_launch(void* const* d_in, const int* in_sizes, int n_in,
                              void* d_out, int out_size, void* d_ws, size_t ws_size,
                              hipStream_t stream)
{
    const float* x     = (const float*)d_in[0];
    const int*   batch = (const int*)d_in[1];
    const float* w1    = (const float*)d_in[2];
    const float* w2    = (const float*)d_in[3];
    const int n_nodes  = in_sizes[1];
    float* out = (float*)d_out;

    float* scores = (float*)d_ws;                          // n*8 floats
    float* gmax   = scores + (size_t)n_nodes * 8;          // GG*8
    float* ginv   = gmax + (size_t)GG * 8;                 // GG*8
    int*   seg    = (int*)(ginv + (size_t)GG * 8);         // GG+1 ints

    const int ntile = (n_nodes + 63) / 64;
    hipLaunchKernelGGL(seg_kernel,     dim3((n_nodes + 255) / 256), dim3(256), 0, stream, batch, seg, n_nodes);
    hipLaunchKernelGGL(score_kernel,   dim3(768), dim3(512), 0, stream, x, w1, w2, scores, n_nodes, ntile);
    hipLaunchKernelGGL(segstat_kernel, dim3(GG),  dim3(256), 0, stream, scores, seg, gmax, ginv);
    hipLaunchKernelGGL(out_kernel,     dim3(GG),  dim3(256), 0, stream, x, scores, seg, gmax, ginv, out);
}